// Round 3
// baseline (856.555 us; speedup 1.0000x reference)
//
#include <hip/hip_runtime.h>

#define N_NODES 100000
#define N_EDGES 20000
#define NNZ_CNT 1000000
#define D 64

// ---------------- CSR build: histogram ----------------
__global__ void k_hist(const int* __restrict__ vertex, const int* __restrict__ edges,
                       int* __restrict__ e_off, int* __restrict__ v_off) {
    int i = blockIdx.x * blockDim.x + threadIdx.x;
    if (i < NNZ_CNT) {
        atomicAdd(&e_off[edges[i] + 1], 1);
        atomicAdd(&v_off[vertex[i] + 1], 1);
    }
}

// ---------------- in-place inclusive scan (single block, n <= 1024*chunk) ----------------
__global__ void k_scan(int* __restrict__ a, int n) {
    __shared__ int part[1024];
    int t = threadIdx.x;
    int chunk = (n + 1023) >> 10;
    int lo = t * chunk;
    int hi = min(lo + chunk, n);
    int s = 0;
    for (int i = lo; i < hi; ++i) s += a[i];
    part[t] = s;
    __syncthreads();
    if (t == 0) {
        int run = 0;
        for (int i = 0; i < 1024; ++i) { int v = part[i]; part[i] = run; run += v; }
    }
    __syncthreads();
    int run = part[t];
    for (int i = lo; i < hi; ++i) { run += a[i]; a[i] = run; }
}

// ---------------- CSR build: scatter indices ----------------
__global__ void k_scatter_build(const int* __restrict__ vertex, const int* __restrict__ edges,
                                int* __restrict__ e_cur, int* __restrict__ v_cur,
                                int* __restrict__ e_list, int* __restrict__ v_list) {
    int i = blockIdx.x * blockDim.x + threadIdx.x;
    if (i < NNZ_CNT) {
        int v = vertex[i], e = edges[i];
        int p = atomicAdd(&e_cur[e], 1);
        e_list[p] = v;
        int q = atomicAdd(&v_cur[v], 1);
        v_list[q] = e;
    }
}

// ---------------- XW1 = X @ W1^T + b1 (grid-stride, W1 staged once/block) ----------------
__global__ void k_xw1(const float* __restrict__ X, const float* __restrict__ W1,
                      const float* __restrict__ b1, float* __restrict__ XW1) {
    __shared__ float Ws[D][D + 1];   // stride 65: (65c+k)%32=(c+k)%32 -> 2-way, free
    __shared__ float Xs[4 * D];
    int t = threadIdx.x;
    for (int i = t; i < D * D; i += 256) Ws[i >> 6][i & 63] = W1[i];
    int r = t >> 6, c = t & 63;
    float bc = b1[c];
    for (int g0 = blockIdx.x; g0 < N_NODES / 4; g0 += gridDim.x) {
        int base = g0 * 4 * D;
        __syncthreads();
        Xs[t] = X[base + t];
        __syncthreads();
        const float* xr = &Xs[r * D];
        float acc = bc;
#pragma unroll
        for (int k = 0; k < D; ++k) acc += xr[k] * Ws[c][k];
        XW1[base + t] = acc;
    }
}

// ---------------- Xe[e] = sum over edge's vertex list of XW1[v] ----------------
__global__ void k_edge_sum(const int* __restrict__ e_off, const int* __restrict__ e_list,
                           const float* __restrict__ XW1, float* __restrict__ Xe) {
    int lane = threadIdx.x & 63;
    int e = (blockIdx.x * blockDim.x + threadIdx.x) >> 6;
    if (e >= N_EDGES) return;
    int beg = e_off[e], end = e_off[e + 1];
    float acc = 0.f;
    int j = beg;
    for (; j + 8 <= end; j += 8) {   // 8-deep independent gathers for MLP
        int v0 = e_list[j + 0], v1 = e_list[j + 1], v2 = e_list[j + 2], v3 = e_list[j + 3];
        int v4 = e_list[j + 4], v5 = e_list[j + 5], v6 = e_list[j + 6], v7 = e_list[j + 7];
        float a0 = XW1[v0 * D + lane], a1 = XW1[v1 * D + lane];
        float a2 = XW1[v2 * D + lane], a3 = XW1[v3 * D + lane];
        float a4 = XW1[v4 * D + lane], a5 = XW1[v5 * D + lane];
        float a6 = XW1[v6 * D + lane], a7 = XW1[v7 * D + lane];
        acc += ((a0 + a1) + (a2 + a3)) + ((a4 + a5) + (a6 + a7));
    }
    for (; j < end; ++j) acc += XW1[e_list[j] * D + lane];
    Xe[e * D + lane] = acc;
}

// ---------------- per-node: g = sum Xe[e]; fused epilogue -> out ----------------
__global__ void __launch_bounds__(256)
k_node_final(const float* __restrict__ X, const float* __restrict__ X0,
             const int* __restrict__ v_off, const int* __restrict__ v_list,
             const float* __restrict__ Xe,
             const float* __restrict__ W2, const float* __restrict__ b2,
             const float* __restrict__ W, const float* __restrict__ bw,
             float* __restrict__ out) {
    __shared__ float W2a[D][D + 1];
    __shared__ float W2b[D][D + 1];
    __shared__ float Wm[D][D + 1];
    __shared__ float xs[4][D];
    __shared__ float gs[4][D];
    __shared__ float ms[4][D];
    int t = threadIdx.x;
    for (int i = t; i < D * D; i += 256) {
        int c = i >> 6, k = i & 63;
        W2a[c][k] = W2[c * 128 + k];
        W2b[c][k] = W2[c * 128 + 64 + k];
        Wm[c][k] = W[i];
    }
    __syncthreads();
    int w = t >> 6, lane = t & 63;
    int v0 = (blockIdx.x << 2) + w;
    int stride = gridDim.x << 2;          // gridDim chosen so trips are uniform
    float b2c = b2[lane], bwc = bw[lane];
    for (int v = v0; v < N_NODES; v += stride) {
        int beg = v_off[v], end = v_off[v + 1];
        float d = (float)(end - beg);
        float g = 0.f;
        int j = beg;
        for (; j + 4 <= end; j += 4) {
            int e0 = v_list[j], e1 = v_list[j + 1], e2 = v_list[j + 2], e3 = v_list[j + 3];
            float a0 = Xe[e0 * D + lane], a1 = Xe[e1 * D + lane];
            float a2 = Xe[e2 * D + lane], a3 = Xe[e3 * D + lane];
            g += (a0 + a1) + (a2 + a3);
        }
        for (; j < end; ++j) g += Xe[v_list[j] * D + lane];
        xs[w][lane] = d * X[v * D + lane];
        gs[w][lane] = g;
        __syncthreads();
        float acc = d * b2c;
#pragma unroll
        for (int k = 0; k < D; ++k) acc += xs[w][k] * W2a[lane][k] + gs[w][k] * W2b[lane][k];
        ms[w][lane] = 0.5f * acc + 0.5f * X0[v * D + lane];
        __syncthreads();
        float o = bwc;
#pragma unroll
        for (int k = 0; k < D; ++k) o += ms[w][k] * Wm[lane][k];
        out[v * D + lane] = o;
    }
}

extern "C" void kernel_launch(void* const* d_in, const int* in_sizes, int n_in,
                              void* d_out, int out_size, void* d_ws, size_t ws_size,
                              hipStream_t stream) {
    const float* X  = (const float*)d_in[0];
    const float* X0 = (const float*)d_in[1];
    const int* vertex = (const int*)d_in[2];
    const int* edges  = (const int*)d_in[3];
    const float* W1w = (const float*)d_in[4];
    const float* W1b = (const float*)d_in[5];
    const float* W2w = (const float*)d_in[6];
    const float* W2bias = (const float*)d_in[7];
    const float* Ww  = (const float*)d_in[8];
    const float* Wbias = (const float*)d_in[9];

    float* out = (float*)d_out;                     // N*64
    float* Xe  = out + (size_t)N_NODES * D;         // E*64 (second output)

    // workspace layout (byte offsets, 256-aligned)
    char* ws = (char*)d_ws;
    float* xw1  = (float*)(ws);                                      // 25,600,000 B
    int* e_off  = (int*)(ws + 25600000);                             // (E+1)*4
    int* v_off  = (int*)(ws + 25600000 + 80128);                     // (N+1)*4
    int* e_cur  = (int*)(ws + 25600000 + 80128 + 400128);            // E*4
    int* v_cur  = (int*)(ws + 25600000 + 80128 + 400128 + 80128);    // N*4
    int* e_list = (int*)(ws + 25600000 + 80128 + 400128 + 80128 + 400128);
    int* v_list = (int*)(ws + 25600000 + 80128 + 400128 + 80128 + 400128 + 4000000);

    hipMemsetAsync(e_off, 0, (N_EDGES + 1) * sizeof(int), stream);
    hipMemsetAsync(v_off, 0, (N_NODES + 1) * sizeof(int), stream);

    // CSR build
    k_hist<<<(NNZ_CNT + 255) / 256, 256, 0, stream>>>(vertex, edges, e_off, v_off);
    k_scan<<<1, 1024, 0, stream>>>(e_off, N_EDGES + 1);
    k_scan<<<1, 1024, 0, stream>>>(v_off, N_NODES + 1);
    hipMemcpyAsync(e_cur, e_off, N_EDGES * sizeof(int), hipMemcpyDeviceToDevice, stream);
    hipMemcpyAsync(v_cur, v_off, N_NODES * sizeof(int), hipMemcpyDeviceToDevice, stream);
    k_scatter_build<<<(NNZ_CNT + 255) / 256, 256, 0, stream>>>(vertex, edges, e_cur, v_cur, e_list, v_list);

    // dense phase
    k_xw1<<<1024, 256, 0, stream>>>(X, W1w, W1b, xw1);
    k_edge_sum<<<(N_EDGES * 64) / 256, 256, 0, stream>>>(e_off, e_list, xw1, Xe);
    k_node_final<<<1250, 256, 0, stream>>>(X, X0, v_off, v_list, Xe,
                                           W2w, W2bias, Ww, Wbias, out);
}

// Round 4
// 818.567 us; speedup vs baseline: 1.0464x; 1.0464x over previous
//
#include <hip/hip_runtime.h>

#define N_NODES 100000
#define N_EDGES 20000
#define NNZ_CNT 1000000
#define D 64

// ---------------- tiny: A = 0.5*W2a^T W^T, B = 0.5*W2b^T W^T, c2 = 0.5*b2 W^T ----------------
// A[k*64+c] = 0.5 * sum_j W2[j*128+k]    * W[c*64+j]
// B[k*64+c] = 0.5 * sum_j W2[j*128+64+k] * W[c*64+j]
__global__ void k_combine(const float* __restrict__ W2, const float* __restrict__ b2,
                          const float* __restrict__ W,
                          float* __restrict__ A, float* __restrict__ B, float* __restrict__ c2) {
    __shared__ float W2s[64 * 129];
    __shared__ float Ws[64 * 65];
    __shared__ float b2s[64];
    int t = threadIdx.x;
    for (int i = t; i < 64 * 128; i += 256) W2s[(i >> 7) * 129 + (i & 127)] = W2[i];
    for (int i = t; i < 64 * 64; i += 256) Ws[(i >> 6) * 65 + (i & 63)] = W[i];
    if (t < 64) b2s[t] = b2[t];
    __syncthreads();
    int c = t & 63, kg = t >> 6;
    for (int kk = 0; kk < 16; ++kk) {
        int k = kg * 16 + kk;
        float a = 0.f, b = 0.f;
        for (int j = 0; j < 64; ++j) {
            float w = Ws[c * 65 + j];
            a += W2s[j * 129 + k] * w;
            b += W2s[j * 129 + 64 + k] * w;
        }
        A[k * 64 + c] = 0.5f * a;
        B[k * 64 + c] = 0.5f * b;
    }
    if (t < 64) {
        float s = 0.f;
        for (int j = 0; j < 64; ++j) s += b2s[j] * Ws[t * 65 + j];
        c2[t] = 0.5f * s;
    }
}

// ---------------- CSR build: histogram ----------------
__global__ void k_hist(const int* __restrict__ vertex, const int* __restrict__ edges,
                       int* __restrict__ e_off, int* __restrict__ v_off) {
    int i = blockIdx.x * blockDim.x + threadIdx.x;
    if (i < NNZ_CNT) {
        atomicAdd(&e_off[edges[i] + 1], 1);
        atomicAdd(&v_off[vertex[i] + 1], 1);
    }
}

// ---------------- dual in-place inclusive scan + cur copy (block0: e, block1: v) ----------------
__global__ void k_scan2(int* __restrict__ e_off, int* __restrict__ e_cur,
                        int* __restrict__ v_off, int* __restrict__ v_cur) {
    int* a;  int n;  int* cur;
    if (blockIdx.x == 0) { a = e_off; n = N_EDGES + 1; cur = e_cur; }
    else                 { a = v_off; n = N_NODES + 1; cur = v_cur; }
    __shared__ int part[1024];
    __shared__ int wsum[16];
    int t = threadIdx.x;
    int chunk = (n + 1023) >> 10;
    int lo = t * chunk;
    int hi = min(lo + chunk, n);
    int s = 0;
    for (int i = lo; i < hi; ++i) s += a[i];
    part[t] = s;
    __syncthreads();
    // two-level shfl scan of part[1024]
    int lane = t & 63, wid = t >> 6;
    int val = part[t];
    int inc = val;
    for (int d = 1; d < 64; d <<= 1) {
        int u = __shfl_up(inc, d);
        if (lane >= d) inc += u;
    }
    if (lane == 63) wsum[wid] = inc;
    __syncthreads();
    if (t < 16) {
        int u = wsum[t];
        for (int d = 1; d < 16; d <<= 1) {
            int x = __shfl_up(u, d);
            if (t >= d) u += x;
        }
        wsum[t] = u;
    }
    __syncthreads();
    int run = inc - val + (wid ? wsum[wid - 1] : 0);   // exclusive prefix over chunks
    for (int i = lo; i < hi; ++i) {
        run += a[i];
        a[i] = run;
        if (i < n - 1) cur[i] = run;
    }
}

// ---------------- CSR build: scatter indices ----------------
__global__ void k_scatter_build(const int* __restrict__ vertex, const int* __restrict__ edges,
                                int* __restrict__ e_cur, int* __restrict__ v_cur,
                                int* __restrict__ e_list, int* __restrict__ v_list) {
    int i = blockIdx.x * blockDim.x + threadIdx.x;
    if (i < NNZ_CNT) {
        int v = vertex[i], e = edges[i];
        int p = atomicAdd(&e_cur[e], 1);
        e_list[p] = v;
        int q = atomicAdd(&v_cur[v], 1);
        v_list[q] = e;
    }
}

// ---------------- dense: zfull[v] = deg*(x@A + c2) + 0.5*x0@W^T + bw  -> written to OUT ----------------
__global__ void __launch_bounds__(256) k_pre(const float* __restrict__ X, const float* __restrict__ X0,
                                             const int* __restrict__ v_off,
                                             const float* __restrict__ A, const float* __restrict__ c2,
                                             const float* __restrict__ W, const float* __restrict__ bw,
                                             float* __restrict__ zfull) {
    __shared__ float As[64 * 65];
    __shared__ float Ws[64 * 65];
    __shared__ float xs[256], x0s[256];
    int t = threadIdx.x;
    for (int i = t; i < 4096; i += 256) {
        As[(i >> 6) * 65 + (i & 63)] = A[i];
        Ws[(i >> 6) * 65 + (i & 63)] = W[i];
    }
    int w = t >> 6, c = t & 63;
    float c2c = c2[c], bwc = bw[c];
    __syncthreads();
    for (int g = blockIdx.x; g < N_NODES / 4; g += gridDim.x) {
        int base = g * 256;
        xs[t] = X[base + t];
        x0s[t] = X0[base + t];
        __syncthreads();
        int v = g * 4 + w;
        float d = (float)(v_off[v + 1] - v_off[v]);
        float accA = 0.f, acc0 = 0.f;
#pragma unroll
        for (int k = 0; k < 64; ++k) {
            accA += xs[w * 64 + k] * As[k * 65 + c];
            acc0 += x0s[w * 64 + k] * Ws[c * 65 + k];
        }
        zfull[base + t] = d * (accA + c2c) + 0.5f * acc0 + bwc;
        __syncthreads();
    }
}

// ---------------- Se[e] = sum of raw X rows over edge's vertex list ----------------
__global__ void k_edge_gather(const int* __restrict__ e_off, const int* __restrict__ e_list,
                              const float* __restrict__ X, float* __restrict__ Se) {
    int lane = threadIdx.x & 63;
    int e = (blockIdx.x * blockDim.x + threadIdx.x) >> 6;
    if (e >= N_EDGES) return;
    int beg = e_off[e], end = e_off[e + 1];
    float acc = 0.f;
    int j = beg;
    for (; j + 8 <= end; j += 8) {
        int v0 = e_list[j + 0], v1 = e_list[j + 1], v2 = e_list[j + 2], v3 = e_list[j + 3];
        int v4 = e_list[j + 4], v5 = e_list[j + 5], v6 = e_list[j + 6], v7 = e_list[j + 7];
        float a0 = X[v0 * D + lane], a1 = X[v1 * D + lane];
        float a2 = X[v2 * D + lane], a3 = X[v3 * D + lane];
        float a4 = X[v4 * D + lane], a5 = X[v5 * D + lane];
        float a6 = X[v6 * D + lane], a7 = X[v7 * D + lane];
        acc += ((a0 + a1) + (a2 + a3)) + ((a4 + a5) + (a6 + a7));
    }
    for (; j < end; ++j) acc += X[e_list[j] * D + lane];
    Se[e * D + lane] = acc;
}

// ---------------- Xe = Se@W1^T + deg_e*b1 (OUTPUT);  Ye = Xe@B ----------------
__global__ void __launch_bounds__(256) k_xe_ye(const float* __restrict__ Se, const int* __restrict__ e_off,
                                               const float* __restrict__ W1, const float* __restrict__ b1,
                                               const float* __restrict__ B,
                                               float* __restrict__ Xe, float* __restrict__ Ye) {
    __shared__ float W1s[64 * 65];
    __shared__ float Bs[64 * 65];
    __shared__ float ses[256];
    __shared__ float xes[256];
    int t = threadIdx.x;
    for (int i = t; i < 4096; i += 256) {
        W1s[(i >> 6) * 65 + (i & 63)] = W1[i];
        Bs[(i >> 6) * 65 + (i & 63)] = B[i];
    }
    int w = t >> 6, c = t & 63;
    float b1c = b1[c];
    __syncthreads();
    for (int g = blockIdx.x; g < N_EDGES / 4; g += gridDim.x) {
        int base = g * 256;
        ses[t] = Se[base + t];
        __syncthreads();
        int e = g * 4 + w;
        float de = (float)(e_off[e + 1] - e_off[e]);
        float acc = 0.f;
#pragma unroll
        for (int k = 0; k < 64; ++k) acc += ses[w * 64 + k] * W1s[c * 65 + k];
        float xe = acc + de * b1c;
        Xe[base + t] = xe;
        xes[t] = xe;
        __syncthreads();
        float accy = 0.f;
#pragma unroll
        for (int k = 0; k < 64; ++k) accy += xes[w * 64 + k] * Bs[k * 65 + c];
        Ye[base + t] = accy;
        __syncthreads();
    }
}

// ---------------- out[v] = zfull[v] (already in out) + sum of Ye rows ----------------
__global__ void k_node_out(const int* __restrict__ v_off, const int* __restrict__ v_list,
                           const float* __restrict__ Ye, float* __restrict__ out) {
    int lane = threadIdx.x & 63;
    int v = (blockIdx.x * blockDim.x + threadIdx.x) >> 6;
    if (v >= N_NODES) return;
    int beg = v_off[v], end = v_off[v + 1];
    float acc = out[v * D + lane];   // zfull written by k_pre
    int j = beg;
    for (; j + 4 <= end; j += 4) {
        int e0 = v_list[j], e1 = v_list[j + 1], e2 = v_list[j + 2], e3 = v_list[j + 3];
        float a0 = Ye[e0 * D + lane], a1 = Ye[e1 * D + lane];
        float a2 = Ye[e2 * D + lane], a3 = Ye[e3 * D + lane];
        acc += (a0 + a1) + (a2 + a3);
    }
    for (; j < end; ++j) acc += Ye[v_list[j] * D + lane];
    out[v * D + lane] = acc;
}

extern "C" void kernel_launch(void* const* d_in, const int* in_sizes, int n_in,
                              void* d_out, int out_size, void* d_ws, size_t ws_size,
                              hipStream_t stream) {
    const float* X  = (const float*)d_in[0];
    const float* X0 = (const float*)d_in[1];
    const int* vertex = (const int*)d_in[2];
    const int* edges  = (const int*)d_in[3];
    const float* W1w = (const float*)d_in[4];
    const float* W1b = (const float*)d_in[5];
    const float* W2w = (const float*)d_in[6];
    const float* W2bias = (const float*)d_in[7];
    const float* Ww  = (const float*)d_in[8];
    const float* Wbias = (const float*)d_in[9];

    float* out = (float*)d_out;                     // N*64 (zfull lives here, then final out)
    float* Xe  = out + (size_t)N_NODES * D;         // E*64 (second output)

    // workspace layout (byte offsets; every size is a multiple of 256)
    char* ws = (char*)d_ws;
    float* Se   = (float*)(ws);                      //  5,120,000
    float* Ye   = (float*)(ws + 5120000);            //  5,120,000
    float* A    = (float*)(ws + 10240000);           //     16,384
    float* Bm   = (float*)(ws + 10256384);           //     16,384
    float* c2   = (float*)(ws + 10272768);           //        256
    int* e_off  = (int*)(ws + 10273024);             //     80,128
    int* v_off  = (int*)(ws + 10353152);             //    400,128
    int* e_cur  = (int*)(ws + 10753280);             //     80,128
    int* v_cur  = (int*)(ws + 10833408);             //    400,128
    int* e_list = (int*)(ws + 11233536);             //  4,000,000
    int* v_list = (int*)(ws + 15233536);             //  4,000,000  (end: 19,233,536)

    hipMemsetAsync(e_off, 0, (N_EDGES + 1) * sizeof(int), stream);
    hipMemsetAsync(v_off, 0, (N_NODES + 1) * sizeof(int), stream);

    k_combine<<<1, 256, 0, stream>>>(W2w, W2bias, Ww, A, Bm, c2);
    k_hist<<<(NNZ_CNT + 255) / 256, 256, 0, stream>>>(vertex, edges, e_off, v_off);
    k_scan2<<<2, 1024, 0, stream>>>(e_off, e_cur, v_off, v_cur);
    k_scatter_build<<<(NNZ_CNT + 255) / 256, 256, 0, stream>>>(vertex, edges, e_cur, v_cur, e_list, v_list);

    k_pre<<<2048, 256, 0, stream>>>(X, X0, v_off, A, c2, Ww, Wbias, out);
    k_edge_gather<<<(N_EDGES * 64) / 256, 256, 0, stream>>>(e_off, e_list, X, Se);
    k_xe_ye<<<1024, 256, 0, stream>>>(Se, e_off, W1w, W1b, Bm, Xe, Ye);
    k_node_out<<<(N_NODES * 64) / 256, 256, 0, stream>>>(v_off, v_list, Ye, out);
}

// Round 5
// 591.978 us; speedup vs baseline: 1.4469x; 1.3828x over previous
//
#include <hip/hip_runtime.h>

#define N_NODES 100000
#define N_EDGES 20000
#define NNZ_CNT 1000000
#define D 64
#define TILE 4096
#define NT_E 5    // ceil((N_EDGES+1)/TILE)
#define NT_V 25   // ceil((N_NODES+1)/TILE)

__device__ __forceinline__ unsigned short f2bf(float f) {
    unsigned int b = __float_as_uint(f);
    return (unsigned short)((b + 0x7fffu + ((b >> 16) & 1u)) >> 16);   // RNE
}
__device__ __forceinline__ float bflo(unsigned int u) { return __uint_as_float(u << 16); }
__device__ __forceinline__ float bfhi(unsigned int u) { return __uint_as_float(u & 0xffff0000u); }

// ---------------- tiny: A = 0.5*W2a^T W^T, B = 0.5*W2b^T W^T, c2 = 0.5*b2 W^T ----------------
__global__ void k_combine(const float* __restrict__ W2, const float* __restrict__ b2,
                          const float* __restrict__ W,
                          float* __restrict__ A, float* __restrict__ B, float* __restrict__ c2) {
    __shared__ float W2s[64 * 129];
    __shared__ float Ws[64 * 65];
    __shared__ float b2s[64];
    int t = threadIdx.x;
    for (int i = t; i < 64 * 128; i += 256) W2s[(i >> 7) * 129 + (i & 127)] = W2[i];
    for (int i = t; i < 64 * 64; i += 256) Ws[(i >> 6) * 65 + (i & 63)] = W[i];
    if (t < 64) b2s[t] = b2[t];
    __syncthreads();
    int c = t & 63, kg = t >> 6;
    for (int kk = 0; kk < 16; ++kk) {
        int k = kg * 16 + kk;
        float a = 0.f, b = 0.f;
        for (int j = 0; j < 64; ++j) {
            float w = Ws[c * 65 + j];
            a += W2s[j * 129 + k] * w;
            b += W2s[j * 129 + 64 + k] * w;
        }
        A[k * 64 + c] = 0.5f * a;
        B[k * 64 + c] = 0.5f * b;
    }
    if (t < 64) {
        float s = 0.f;
        for (int j = 0; j < 64; ++j) s += b2s[j] * Ws[t * 65 + j];
        c2[t] = 0.5f * s;
    }
}

// ---------------- CSR build: histogram ----------------
__global__ void k_hist(const int* __restrict__ vertex, const int* __restrict__ edges,
                       int* __restrict__ e_off, int* __restrict__ v_off) {
    int i = blockIdx.x * blockDim.x + threadIdx.x;
    if (i < NNZ_CNT) {
        atomicAdd(&e_off[edges[i] + 1], 1);
        atomicAdd(&v_off[vertex[i] + 1], 1);
    }
}

// ---------------- parallel scan, pass 1: per-tile inclusive scan + tile sums ----------------
__global__ void __launch_bounds__(1024) k_scan_s1(int* __restrict__ e_off, int* __restrict__ v_off,
                                                  int* __restrict__ bsum) {
    int b = blockIdx.x;
    int* a; int n; int bi;
    if (b < NT_E) { a = e_off; n = N_EDGES + 1; bi = b; }
    else          { a = v_off; n = N_NODES + 1; bi = b - NT_E; }
    int t = threadIdx.x;
    int idx = bi * TILE + t * 4;
    int x0 = 0, x1 = 0, x2 = 0, x3 = 0;
    if (idx + 3 < n) { int4 v = *(const int4*)(a + idx); x0 = v.x; x1 = v.y; x2 = v.z; x3 = v.w; }
    else {
        if (idx < n) x0 = a[idx];
        if (idx + 1 < n) x1 = a[idx + 1];
        if (idx + 2 < n) x2 = a[idx + 2];
        if (idx + 3 < n) x3 = a[idx + 3];
    }
    int s = x0 + x1 + x2 + x3;
    int lane = t & 63, wid = t >> 6;
    int inc = s;
    for (int d = 1; d < 64; d <<= 1) { int u = __shfl_up(inc, d); if (lane >= d) inc += u; }
    __shared__ int wtot[16];
    if (lane == 63) wtot[wid] = inc;
    __syncthreads();
    if (t < 16) {
        int u = wtot[t];
        for (int d = 1; d < 16; d <<= 1) { int x = __shfl_up(u, d); if (t >= d) u += x; }
        wtot[t] = u;
    }
    __syncthreads();
    int base = inc - s + (wid ? wtot[wid - 1] : 0);
    int r0 = base + x0, r1 = r0 + x1, r2 = r1 + x2, r3 = r2 + x3;
    if (idx + 3 < n) { *(int4*)(a + idx) = make_int4(r0, r1, r2, r3); }
    else {
        if (idx < n) a[idx] = r0;
        if (idx + 1 < n) a[idx + 1] = r1;
        if (idx + 2 < n) a[idx + 2] = r2;
        if (idx + 3 < n) a[idx + 3] = r3;
    }
    if (t == 1023) bsum[b] = r3;
}

// ---------------- scan pass 2: add tile offsets, emit cur copies ----------------
__global__ void __launch_bounds__(1024) k_scan_s3(int* __restrict__ e_off, int* __restrict__ v_off,
                                                  int* __restrict__ e_cur, int* __restrict__ v_cur,
                                                  const int* __restrict__ bsum) {
    int b = blockIdx.x;
    int* a; int n; int bi; int* cur; int sb;
    if (b < NT_E) { a = e_off; n = N_EDGES + 1; bi = b; cur = e_cur; sb = 0; }
    else          { a = v_off; n = N_NODES + 1; bi = b - NT_E; cur = v_cur; sb = NT_E; }
    int off = 0;
    for (int j = sb; j < sb + bi; ++j) off += bsum[j];
    int t = threadIdx.x;
    int idx = bi * TILE + t * 4;
    if (idx + 3 < n - 1) {
        int4 v = *(const int4*)(a + idx);
        v.x += off; v.y += off; v.z += off; v.w += off;
        *(int4*)(a + idx) = v;
        *(int4*)(cur + idx) = v;
    } else {
        for (int k = 0; k < 4; ++k) {
            int i = idx + k;
            if (i < n) {
                int vv = a[i] + off;
                a[i] = vv;
                if (i < n - 1) cur[i] = vv;
            }
        }
    }
}

// ---------------- CSR build: scatter indices ----------------
__global__ void k_scatter_build(const int* __restrict__ vertex, const int* __restrict__ edges,
                                int* __restrict__ e_cur, int* __restrict__ v_cur,
                                int* __restrict__ e_list, int* __restrict__ v_list) {
    int i = blockIdx.x * blockDim.x + threadIdx.x;
    if (i < NNZ_CNT) {
        int v = vertex[i], e = edges[i];
        int p = atomicAdd(&e_cur[e], 1);
        e_list[p] = v;
        int q = atomicAdd(&v_cur[v], 1);
        v_list[q] = e;
    }
}

// ---------------- dense: zfull = deg*(x@A+c2) + 0.5*x0@W^T + bw -> OUT; also emit X16 ----------------
__global__ void __launch_bounds__(256) k_pre(const float* __restrict__ X, const float* __restrict__ X0,
                                             const int* __restrict__ v_off,
                                             const float* __restrict__ A, const float* __restrict__ c2,
                                             const float* __restrict__ W, const float* __restrict__ bw,
                                             float* __restrict__ zfull, unsigned short* __restrict__ X16) {
    __shared__ float As[64 * 65];
    __shared__ float Ws[64 * 65];
    __shared__ float xs[256], x0s[256];
    int t = threadIdx.x;
    for (int i = t; i < 4096; i += 256) {
        As[(i >> 6) * 65 + (i & 63)] = A[i];
        Ws[(i >> 6) * 65 + (i & 63)] = W[i];
    }
    int w = t >> 6, c = t & 63;
    float c2c = c2[c], bwc = bw[c];
    __syncthreads();
    for (int g = blockIdx.x; g < N_NODES / 4; g += gridDim.x) {
        int base = g * 256;
        float xv = X[base + t];
        xs[t] = xv;
        X16[base + t] = f2bf(xv);
        x0s[t] = X0[base + t];
        __syncthreads();
        int v = g * 4 + w;
        float d = (float)(v_off[v + 1] - v_off[v]);
        float accA = 0.f, acc0 = 0.f;
#pragma unroll
        for (int k = 0; k < 64; ++k) {
            accA += xs[w * 64 + k] * As[k * 65 + c];
            acc0 += x0s[w * 64 + k] * Ws[c * 65 + k];
        }
        zfull[base + t] = d * (accA + c2c) + 0.5f * acc0 + bwc;
        __syncthreads();
    }
}

// ---------------- Se[e] = sum of bf16 X rows over edge's vertex list ----------------
__global__ void k_edge_gather(const int* __restrict__ e_off, const int* __restrict__ e_list,
                              const unsigned int* __restrict__ X16u, float* __restrict__ Se) {
    int lane = threadIdx.x & 63;
    int e = (blockIdx.x * blockDim.x + threadIdx.x) >> 6;
    if (e >= N_EDGES) return;
    int half = lane >> 5, q = lane & 31;
    int beg = e_off[e], end = e_off[e + 1];
    float a0 = 0.f, a1 = 0.f;
    int j = beg;
    for (; j + 8 <= end; j += 8) {      // 4 pairs -> 4 outstanding row loads/lane
        int v0 = e_list[j + 0 + half], v1 = e_list[j + 2 + half];
        int v2 = e_list[j + 4 + half], v3 = e_list[j + 6 + half];
        unsigned int u0 = X16u[v0 * 32 + q], u1 = X16u[v1 * 32 + q];
        unsigned int u2 = X16u[v2 * 32 + q], u3 = X16u[v3 * 32 + q];
        a0 += (bflo(u0) + bflo(u1)) + (bflo(u2) + bflo(u3));
        a1 += (bfhi(u0) + bfhi(u1)) + (bfhi(u2) + bfhi(u3));
    }
    for (; j + 2 <= end; j += 2) {
        int v = e_list[j + half];
        unsigned int u = X16u[v * 32 + q];
        a0 += bflo(u); a1 += bfhi(u);
    }
    if (j < end && half == 0) {
        unsigned int u = X16u[e_list[j] * 32 + q];
        a0 += bflo(u); a1 += bfhi(u);
    }
    a0 += __shfl_xor(a0, 32);
    a1 += __shfl_xor(a1, 32);
    if (half == 0) {
        ((float2*)(Se + e * D))[q] = make_float2(a0, a1);
    }
}

// ---------------- Xe = Se@W1^T + deg_e*b1 (OUTPUT);  Ye16 = bf16(Xe@B) ----------------
__global__ void __launch_bounds__(256) k_xe_ye(const float* __restrict__ Se, const int* __restrict__ e_off,
                                               const float* __restrict__ W1, const float* __restrict__ b1,
                                               const float* __restrict__ B,
                                               float* __restrict__ Xe, unsigned short* __restrict__ Ye16) {
    __shared__ float W1s[64 * 65];
    __shared__ float Bs[64 * 65];
    __shared__ float ses[256];
    __shared__ float xes[256];
    int t = threadIdx.x;
    for (int i = t; i < 4096; i += 256) {
        W1s[(i >> 6) * 65 + (i & 63)] = W1[i];
        Bs[(i >> 6) * 65 + (i & 63)] = B[i];
    }
    int w = t >> 6, c = t & 63;
    float b1c = b1[c];
    __syncthreads();
    for (int g = blockIdx.x; g < N_EDGES / 4; g += gridDim.x) {
        int base = g * 256;
        ses[t] = Se[base + t];
        __syncthreads();
        int e = g * 4 + w;
        float de = (float)(e_off[e + 1] - e_off[e]);
        float acc = 0.f;
#pragma unroll
        for (int k = 0; k < 64; ++k) acc += ses[w * 64 + k] * W1s[c * 65 + k];
        float xe = acc + de * b1c;
        Xe[base + t] = xe;
        xes[t] = xe;
        __syncthreads();
        float accy = 0.f;
#pragma unroll
        for (int k = 0; k < 64; ++k) accy += xes[w * 64 + k] * Bs[k * 65 + c];
        Ye16[base + t] = f2bf(accy);
        __syncthreads();
    }
}

// ---------------- out[v] = zfull[v] + sum of bf16 Ye rows ----------------
__global__ void k_node_out(const int* __restrict__ v_off, const int* __restrict__ v_list,
                           const unsigned int* __restrict__ Ye16u, float* __restrict__ out) {
    int lane = threadIdx.x & 63;
    int v = (blockIdx.x * blockDim.x + threadIdx.x) >> 6;
    if (v >= N_NODES) return;
    int half = lane >> 5, q = lane & 31;
    int beg = v_off[v], end = v_off[v + 1];
    float a0 = 0.f, a1 = 0.f;
    int j = beg;
    for (; j + 4 <= end; j += 4) {
        int e0 = v_list[j + half], e1 = v_list[j + 2 + half];
        unsigned int u0 = Ye16u[e0 * 32 + q], u1 = Ye16u[e1 * 32 + q];
        a0 += bflo(u0) + bflo(u1);
        a1 += bfhi(u0) + bfhi(u1);
    }
    for (; j + 2 <= end; j += 2) {
        int e0 = v_list[j + half];
        unsigned int u = Ye16u[e0 * 32 + q];
        a0 += bflo(u); a1 += bfhi(u);
    }
    if (j < end && half == 0) {
        unsigned int u = Ye16u[v_list[j] * 32 + q];
        a0 += bflo(u); a1 += bfhi(u);
    }
    a0 += __shfl_xor(a0, 32);
    a1 += __shfl_xor(a1, 32);
    if (half == 0) {
        float2* o = (float2*)(out + (size_t)v * D) + q;
        float2 z = *o;
        z.x += a0; z.y += a1;
        *o = z;
    }
}

extern "C" void kernel_launch(void* const* d_in, const int* in_sizes, int n_in,
                              void* d_out, int out_size, void* d_ws, size_t ws_size,
                              hipStream_t stream) {
    const float* X  = (const float*)d_in[0];
    const float* X0 = (const float*)d_in[1];
    const int* vertex = (const int*)d_in[2];
    const int* edges  = (const int*)d_in[3];
    const float* W1w = (const float*)d_in[4];
    const float* W1b = (const float*)d_in[5];
    const float* W2w = (const float*)d_in[6];
    const float* W2bias = (const float*)d_in[7];
    const float* Ww  = (const float*)d_in[8];
    const float* Wbias = (const float*)d_in[9];

    float* out = (float*)d_out;                     // N*64 (zfull -> final out)
    float* Xe  = out + (size_t)N_NODES * D;         // E*64 (second output)

    // workspace layout (all offsets multiples of 256)
    char* ws = (char*)d_ws;
    unsigned short* X16 = (unsigned short*)(ws);            // 12,800,000
    float* Se   = (float*)(ws + 12800000);                  //  5,120,000
    unsigned short* Ye16 = (unsigned short*)(ws + 17920000);//  2,560,000
    float* A    = (float*)(ws + 20480000);                  //     16,384
    float* Bm   = (float*)(ws + 20496384);                  //     16,384
    float* c2   = (float*)(ws + 20512768);                  //        256
    int* e_off  = (int*)(ws + 20513024);                    //     80,128
    int* v_off  = (int*)(ws + 20593152);                    //    400,128
    int* e_cur  = (int*)(ws + 20993280);                    //     80,128
    int* v_cur  = (int*)(ws + 21073408);                    //    400,128
    int* e_list = (int*)(ws + 21473536);                    //  4,000,000
    int* v_list = (int*)(ws + 25473536);                    //  4,000,000
    int* bsum   = (int*)(ws + 29473536);                    //        256

    hipMemsetAsync(e_off, 0, (N_EDGES + 1) * sizeof(int), stream);
    hipMemsetAsync(v_off, 0, (N_NODES + 1) * sizeof(int), stream);

    k_combine<<<1, 256, 0, stream>>>(W2w, W2bias, Ww, A, Bm, c2);
    k_hist<<<(NNZ_CNT + 255) / 256, 256, 0, stream>>>(vertex, edges, e_off, v_off);
    k_scan_s1<<<NT_E + NT_V, 1024, 0, stream>>>(e_off, v_off, bsum);
    k_scan_s3<<<NT_E + NT_V, 1024, 0, stream>>>(e_off, v_off, e_cur, v_cur, bsum);
    k_scatter_build<<<(NNZ_CNT + 255) / 256, 256, 0, stream>>>(vertex, edges, e_cur, v_cur, e_list, v_list);

    k_pre<<<2048, 256, 0, stream>>>(X, X0, v_off, A, c2, Ww, Wbias, out, X16);
    k_edge_gather<<<(N_EDGES * 64) / 256, 256, 0, stream>>>(e_off, e_list, (const unsigned int*)X16, Se);
    k_xe_ye<<<1024, 256, 0, stream>>>(Se, e_off, W1w, W1b, Bm, Xe, Ye16);
    k_node_out<<<(N_NODES * 64) / 256, 256, 0, stream>>>(v_off, v_list, (const unsigned int*)Ye16, out);
}